// Round 1
// baseline (455.200 us; speedup 1.0000x reference)
//
#include <hip/hip_runtime.h>

// CrossTableAttention on MI355X (gfx950)
// T=16 B=1024 D=1024 R=8 H=16 DH=64
//
// Restructured: K/V projections hoisted out of the R gather:
//   Ka[t',b] = X[t',b] @ Wk.T   (no bias); k[t,b,r] = rel_w[t,r]*Ka[idx,b] + bk
// so QKV is ONE bf16 GEMM [16384,1024]x[1024,3072]; attention is tiny fp32;
// output GEMM [16384,1024]x[1024,1024]. Total ~137 GFLOP on the MFMA pipe.

typedef unsigned short u16;
typedef __attribute__((ext_vector_type(8))) short short8;   // 8 bf16 = 4 VGPRs (guide §3)
typedef __attribute__((ext_vector_type(4))) float f32x4;

__device__ __forceinline__ float bf2f(u16 u) {
  unsigned int x = ((unsigned int)u) << 16;
  return __uint_as_float(x);
}
__device__ __forceinline__ u16 f2bf(float f) {
  unsigned int x = __float_as_uint(f);
  unsigned int r = (x + 0x7fffu + ((x >> 16) & 1u)) >> 16;   // RNE
  return (u16)r;
}

// async global->LDS, 16B per lane; lds dest is wave-uniform base + lane*16
__device__ __forceinline__ void gld_lds16(const void* g, void* l) {
  __builtin_amdgcn_global_load_lds(
      (const __attribute__((address_space(1))) unsigned int*)(unsigned long long)g,
      (__attribute__((address_space(3))) unsigned int*)(unsigned int)(unsigned long long)l,
      16, 0, 0);
}

// ---------------------------------------------------------------- prep kernels

__global__ void relw_kernel(const float* __restrict__ rel_embs,
                            const float* __restrict__ w_rel,
                            const float* __restrict__ b_rel,
                            float* __restrict__ rel_w) {
  const int tr = blockIdx.x;            // t*8 + r, 128 total
  const float* row = rel_embs + (size_t)tr * 1024;
  const int lane = threadIdx.x;         // 64 threads
  float s = 0.f;
  for (int i = lane; i < 1024; i += 64) s += row[i] * w_rel[i];
  for (int off = 32; off > 0; off >>= 1) s += __shfl_down(s, off, 64);
  if (lane == 0) rel_w[tr] = 1.f / (1.f + __expf(-(s + b_rel[0])));
}

__global__ void cvt_f32_bf16(const float* __restrict__ in, u16* __restrict__ out, int n4) {
  int i = blockIdx.x * blockDim.x + threadIdx.x;
  if (i >= n4) return;
  float4 v = ((const float4*)in)[i];
  ushort4 o;
  o.x = f2bf(v.x); o.y = f2bf(v.y); o.z = f2bf(v.z); o.w = f2bf(v.w);
  ((ushort4*)out)[i] = o;
}

// ---------------------------------------------------------------- GEMM mainloop
// A [M,K] row-major bf16, B [N,K] row-major bf16 (i.e. W as given: out = x@W.T)
// 128x128 block tile, BK=32, 4 waves, each wave 64x64 = 4x4 mfma_16x16x32 tiles.

__device__ __forceinline__ void gemm_mainloop(const u16* __restrict__ A,
                                              const u16* __restrict__ B,
                                              u16* As, u16* Bs,
                                              int m0, int n0, int K,
                                              f32x4 (&acc)[4][4]) {
  const int tid  = threadIdx.x;
  const int wave = tid >> 6;
  const int lane = tid & 63;

  // staging: per wave 2 issues of 1KB each for A and B; LDS layout [row][32] contiguous
  const int srow = wave * 32 + (lane >> 2);     // + i*16
  const int scol = (lane & 3) * 8;
  const u16* pa0 = A + (size_t)(m0 + srow) * K + scol;
  const u16* pa1 = pa0 + (size_t)16 * K;
  const u16* pb0 = B + (size_t)(n0 + srow) * K + scol;
  const u16* pb1 = pb0 + (size_t)16 * K;
  u16* la0 = As + wave * 1024;   // wave-uniform LDS bases (elements)
  u16* la1 = la0 + 512;
  u16* lb0 = Bs + wave * 1024;
  u16* lb1 = lb0 + 512;

  const int fr = lane & 15;      // m (A) / n (B) within 16
  const int fq = lane >> 4;      // k-chunk quad
  const int mb = (wave >> 1) * 64;
  const int nb = (wave & 1) * 64;

  for (int k0 = 0; k0 < K; k0 += 32) {
    gld_lds16(pa0, la0); gld_lds16(pa1, la1);
    gld_lds16(pb0, lb0); gld_lds16(pb1, lb1);
    pa0 += 32; pa1 += 32; pb0 += 32; pb1 += 32;
    __syncthreads();               // drains vmcnt (incl. global_load_lds)
    short8 af[4], bg[4];
#pragma unroll
    for (int i = 0; i < 4; ++i) {
      af[i] = *(const short8*)(As + (mb + i * 16 + fr) * 32 + fq * 8);
      bg[i] = *(const short8*)(Bs + (nb + i * 16 + fr) * 32 + fq * 8);
    }
#pragma unroll
    for (int i = 0; i < 4; ++i)
#pragma unroll
      for (int j = 0; j < 4; ++j)
        acc[i][j] = __builtin_amdgcn_mfma_f32_16x16x32_bf16(af[i], bg[j], acc[i][j], 0, 0, 0);
    __syncthreads();
  }
}

// GEMM1: X[16384,1024] @ Wcat[3072,1024].T -> split into Q(+bq)/K/V bf16 buffers
__global__ __launch_bounds__(256)
void gemm_qkv(const u16* __restrict__ A, const u16* __restrict__ B,
              const float* __restrict__ bq,
              u16* __restrict__ Qb, u16* __restrict__ Kb, u16* __restrict__ Vb) {
  __shared__ __align__(16) u16 As[128 * 32];
  __shared__ __align__(16) u16 Bs[128 * 32];
  const int m0 = blockIdx.y * 128;
  const int n0 = blockIdx.x * 128;
  f32x4 acc[4][4];
#pragma unroll
  for (int i = 0; i < 4; ++i)
#pragma unroll
    for (int j = 0; j < 4; ++j) acc[i][j] = (f32x4){0.f, 0.f, 0.f, 0.f};

  gemm_mainloop(A, B, As, Bs, m0, n0, 1024, acc);

  const int lane = threadIdx.x & 63;
  const int wave = threadIdx.x >> 6;
  const int mb = (wave >> 1) * 64, nb = (wave & 1) * 64;
  const int colw = lane & 15, roww = (lane >> 4) * 4;
#pragma unroll
  for (int i = 0; i < 4; ++i) {
#pragma unroll
    for (int j = 0; j < 4; ++j) {
      const int gn  = n0 + nb + j * 16 + colw;     // 0..3071
      const int sel = gn >> 10;                    // uniform per block
      const int nn  = gn & 1023;
#pragma unroll
      for (int r = 0; r < 4; ++r) {
        const int gm = m0 + mb + i * 16 + roww + r;
        const float v = acc[i][j][r];
        const size_t idx = (size_t)gm * 1024 + nn;
        if (sel == 0)      Qb[idx] = f2bf(v + bq[nn]);
        else if (sel == 1) Kb[idx] = f2bf(v);
        else               Vb[idx] = f2bf(v);
      }
    }
  }
}

// GEMM2: ctx[16384,1024] @ Wo[1024,1024].T + bo -> fp32 out
__global__ __launch_bounds__(256)
void gemm_out(const u16* __restrict__ A, const u16* __restrict__ B,
              const float* __restrict__ bo, float* __restrict__ out) {
  __shared__ __align__(16) u16 As[128 * 32];
  __shared__ __align__(16) u16 Bs[128 * 32];
  const int m0 = blockIdx.y * 128;
  const int n0 = blockIdx.x * 128;
  f32x4 acc[4][4];
#pragma unroll
  for (int i = 0; i < 4; ++i)
#pragma unroll
    for (int j = 0; j < 4; ++j) acc[i][j] = (f32x4){0.f, 0.f, 0.f, 0.f};

  gemm_mainloop(A, B, As, Bs, m0, n0, 1024, acc);

  const int lane = threadIdx.x & 63;
  const int wave = threadIdx.x >> 6;
  const int mb = (wave >> 1) * 64, nb = (wave & 1) * 64;
  const int colw = lane & 15, roww = (lane >> 4) * 4;
#pragma unroll
  for (int i = 0; i < 4; ++i) {
#pragma unroll
    for (int j = 0; j < 4; ++j) {
      const int gn = n0 + nb + j * 16 + colw;
#pragma unroll
      for (int r = 0; r < 4; ++r) {
        const int gm = m0 + mb + i * 16 + roww + r;
        out[(size_t)gm * 1024 + gn] = acc[i][j][r] + bo[gn];
      }
    }
  }
}

// ---------------------------------------------------------------- attention
// one block per (t,b); scores over R=8, heads H=16, DH=64; all fp32 math.
// score[h][r] = (rw[r]*(q.Ka_r) + q.bk)/8 ; ctx = sum_r attn*rw*Va_r + bv (softmax sums to 1)
__global__ __launch_bounds__(256)
void attn_kernel(const u16* Qb, const u16* __restrict__ Kb, const u16* __restrict__ Vb,
                 const float* __restrict__ relw, const int* __restrict__ rel_idx,
                 const float* __restrict__ bk, const float* __restrict__ bv,
                 u16* ctx /* aliases Qb: each block only touches its own row */) {
  const int m = blockIdx.x;        // t*1024 + b
  const int t = m >> 10;
  const int b = m & 1023;
  const int tid = threadIdx.x;

  __shared__ float qs[1024];
  __shared__ float sc[16][8];
  __shared__ float qbk[16];
  __shared__ float at[16][8];
  __shared__ float rw[8];
  __shared__ int   ridx[8];

  if (tid < 8) { rw[tid] = relw[t * 8 + tid]; ridx[tid] = rel_idx[t * 8 + tid]; }
  {
    ushort4 u = ((const ushort4*)(Qb + (size_t)m * 1024))[tid];
    qs[tid * 4 + 0] = bf2f(u.x); qs[tid * 4 + 1] = bf2f(u.y);
    qs[tid * 4 + 2] = bf2f(u.z); qs[tid * 4 + 3] = bf2f(u.w);
  }
  __syncthreads();

  if (tid < 128) {                 // raw q.Ka dot per (h,r)
    const int h = tid & 15, r = tid >> 4;
    const u16* krow = Kb + ((size_t)ridx[r] * 1024 + b) * 1024 + h * 64;
    const float* qp = qs + h * 64;
    float s = 0.f;
#pragma unroll
    for (int c = 0; c < 16; ++c) {
      ushort4 u = ((const ushort4*)krow)[c];
      s += qp[c * 4 + 0] * bf2f(u.x) + qp[c * 4 + 1] * bf2f(u.y)
         + qp[c * 4 + 2] * bf2f(u.z) + qp[c * 4 + 3] * bf2f(u.w);
    }
    sc[h][r] = s;
  } else if (tid < 144) {          // q . bk per head
    const int h = tid - 128;
    const float* qp = qs + h * 64;
    const float* bp = bk + h * 64;
    float s = 0.f;
#pragma unroll 8
    for (int d = 0; d < 64; ++d) s += qp[d] * bp[d];
    qbk[h] = s;
  }
  __syncthreads();

  if (tid < 16) {                  // softmax over R=8
    const int h = tid;
    float v[8]; float mx = -1e30f;
#pragma unroll
    for (int r = 0; r < 8; ++r) {
      v[r] = (rw[r] * sc[h][r] + qbk[h]) * 0.125f;
      mx = fmaxf(mx, v[r]);
    }
    float sum = 0.f;
#pragma unroll
    for (int r = 0; r < 8; ++r) { v[r] = __expf(v[r] - mx); sum += v[r]; }
    const float inv = 1.f / sum;
#pragma unroll
    for (int r = 0; r < 8; ++r) at[h][r] = v[r] * inv;
  }
  __syncthreads();

  {                                // ctx: 4 d's per thread
    const int h = tid >> 4;
    float4 o = ((const float4*)bv)[tid];
#pragma unroll
    for (int r = 0; r < 8; ++r) {
      const float w = at[h][r] * rw[r];
      const u16* vrow = Vb + ((size_t)ridx[r] * 1024 + b) * 1024;
      ushort4 u = ((const ushort4*)vrow)[tid];
      o.x += w * bf2f(u.x); o.y += w * bf2f(u.y);
      o.z += w * bf2f(u.z); o.w += w * bf2f(u.w);
    }
    ushort4 res;
    res.x = f2bf(o.x); res.y = f2bf(o.y); res.z = f2bf(o.z); res.w = f2bf(o.w);
    ((ushort4*)(ctx + (size_t)m * 1024))[tid] = res;
  }
}

// ---------------------------------------------------------------- launch

extern "C" void kernel_launch(void* const* d_in, const int* in_sizes, int n_in,
                              void* d_out, int out_size, void* d_ws, size_t ws_size,
                              hipStream_t stream) {
  const float* table = (const float*)d_in[0];
  const float* rele  = (const float*)d_in[1];
  const int*   ridx  = (const int*)d_in[2];
  const float* Wq    = (const float*)d_in[3];
  const float* bq    = (const float*)d_in[4];
  const float* Wk    = (const float*)d_in[5];
  const float* bk    = (const float*)d_in[6];
  const float* Wv    = (const float*)d_in[7];
  const float* bv    = (const float*)d_in[8];
  const float* Wo    = (const float*)d_in[9];
  const float* bo    = (const float*)d_in[10];
  const float* wr    = (const float*)d_in[11];
  const float* br    = (const float*)d_in[12];
  float* out = (float*)d_out;

  char* ws = (char*)d_ws;
  const size_t MB = 1024 * 1024;
  u16*  Xbf  = (u16*)(ws);                    // 32 MB  [16384,1024] bf16
  u16*  Kb   = (u16*)(ws + 32  * MB);         // 32 MB
  u16*  Vb   = (u16*)(ws + 64  * MB);         // 32 MB
  u16*  Qb   = (u16*)(ws + 96  * MB);         // 32 MB (also ctx)
  u16*  Wcat = (u16*)(ws + 128 * MB);         // 6 MB  [3072,1024] bf16 (Wq|Wk|Wv)
  u16*  Wob  = (u16*)(ws + 134 * MB);         // 2 MB
  float* relw = (float*)(ws + 136 * MB);      // 512 B

  relw_kernel<<<128, 64, 0, stream>>>(rele, wr, br, relw);
  cvt_f32_bf16<<<16384, 256, 0, stream>>>(table, Xbf, 4194304);
  cvt_f32_bf16<<<1024, 256, 0, stream>>>(Wq, Wcat,            262144);
  cvt_f32_bf16<<<1024, 256, 0, stream>>>(Wk, Wcat + 1048576,  262144);
  cvt_f32_bf16<<<1024, 256, 0, stream>>>(Wv, Wcat + 2097152,  262144);
  cvt_f32_bf16<<<1024, 256, 0, stream>>>(Wo, Wob,             262144);

  gemm_qkv<<<dim3(24, 128), 256, 0, stream>>>(Xbf, Wcat, bq, Qb, Kb, Vb);
  attn_kernel<<<16384, 256, 0, stream>>>(Qb, Kb, Vb, relw, ridx, bk, bv, Qb);
  gemm_out<<<dim3(8, 128), 256, 0, stream>>>(Qb, Wob, bo, out);
}